// Round 10
// baseline (30697.009 us; speedup 1.0000x reference)
//
#include <hip/hip_runtime.h>

typedef _Float16 f16;
typedef _Float16 f16x8 __attribute__((ext_vector_type(8)));
typedef _Float16 f16x4 __attribute__((ext_vector_type(4)));
typedef float f32x4 __attribute__((ext_vector_type(4)));

#define T_TOT 2048
#define BATCH 64
#define HID 256
#define G3 768
#define WS 32
#define NWIN 64
#define NRING 4
#define IPT 12288                   // f16 per timestep per lg: 3 gates x 256 j x 16 b
#define IPSLOT (WS * IPT)           // 393216 f16 per ring slot

#define NLOG2E -1.44269504088896f   // -log2(e): sigmoid pre-scale
#define P2LOG2E 2.88539008177793f   // +2*log2(e): tanh pre-scale

#define SPIN_BUDGET 20000000L       // bails instead of hanging the queue

// LDS map (64 KB):
//   scan:   [0,48K) kf=7 slab (8 wv x 6 i x 1 KB); [48K,56K) h group A; [56K,64K) h group B
//   worker: [0,64K) As tile
#define WLDS_BYTES 49152
#define SMEM_BYTES 65536

// flags (monotone single-writer counters), zero-initialized:
#define F_YPROG(lg)   (lg)                    // scan l: y windows produced
#define F_IPCONS(lg)  (24 + (lg))             // scan l: ip windows consumed
#define F_IPP(lg,q)   (48 + (lg)*4 + (q))     // worker q of layer l: ip produced
#define F_YC(lg,q)    (144 + (lg)*4 + (q))    // worker q of layer l+1: y consumed

__device__ __forceinline__ float fexp2(float x) { return __builtin_amdgcn_exp2f(x); }
__device__ __forceinline__ float frcp(float x) { return __builtin_amdgcn_rcpf(x); }

// opaque identity: makes a loaded value NON-rematerializable so the register
// allocator must keep it resident (VGPR or AGPR) instead of re-loading each use
__device__ __forceinline__ f16x8 opaque(f16x8 v) {
    f32x4 t = __builtin_bit_cast(f32x4, v);
    asm volatile("" : "+v"(t));
    return __builtin_bit_cast(f16x8, t);
}

__device__ __forceinline__ void st_rel(int* p, int v) {
    __hip_atomic_store(p, v, __ATOMIC_RELEASE, __HIP_MEMORY_SCOPE_AGENT);
}
__device__ __forceinline__ int ld_rlx(int* p) {
    return __hip_atomic_load(p, __ATOMIC_RELAXED, __HIP_MEMORY_SCOPE_AGENT);
}
__device__ __forceinline__ void wait_ge(int* f, int target, int tid, long& budget) {
    if (tid == 0) {
        while (ld_rlx(f) < target) {
            if (--budget < 0) break;
            __builtin_amdgcn_s_sleep(2);
        }
        __builtin_amdgcn_fence(__ATOMIC_ACQUIRE, "agent");
    }
    __syncthreads();
}
__device__ __forceinline__ void wait4_ge(int* f, int target, int tid, long& budget) {
    if (tid == 0) {
        #pragma unroll
        for (int q = 0; q < 4; ++q)
            while (ld_rlx(f + q) < target) {
                if (--budget < 0) break;
                __builtin_amdgcn_s_sleep(2);
            }
        __builtin_amdgcn_fence(__ATOMIC_ACQUIRE, "agent");
    }
    __syncthreads();
}
// barrier draining ONLY LDS ops; global loads/stores stay in flight
__device__ __forceinline__ void bar_lgkm() {
    asm volatile("s_waitcnt lgkmcnt(0)\n\ts_barrier" ::: "memory");
}

__global__ void cvt_f16(const float* __restrict__ s, f16* __restrict__ d, int n) {
    int i = (blockIdx.x * 256 + threadIdx.x) * 4;
    if (i + 3 < n) {
        f32x4 v = *(const f32x4*)(s + i);
        f16x4 o = { (f16)v[0], (f16)v[1], (f16)v[2], (f16)v[3] };
        *(f16x4*)(d + i) = o;
    }
}

// W_hh with gate pre-scale: rows<512 (r,z) * -log2e; rows>=512 (n) * 2log2e
__global__ void cvt_whh(const float* __restrict__ s, f16* __restrict__ d, int n) {
    int i = (blockIdx.x * 256 + threadIdx.x) * 4;
    if (i + 3 < n) {
        int row = (i >> 8) % G3;
        float sc = (row < 512) ? NLOG2E : P2LOG2E;
        f32x4 v = *(const f32x4*)(s + i);
        f16x4 o = { (f16)(v[0] * sc), (f16)(v[1] * sc), (f16)(v[2] * sc), (f16)(v[3] * sc) };
        *(f16x4*)(d + i) = o;
    }
}

// biasc[l][g] = scale_g * (b_ih + b_hh for r,z ; b_ih only for n)
__global__ void bias_prep(const float* __restrict__ bi, const float* __restrict__ bh,
                          float* __restrict__ o) {
    int i = blockIdx.x * 256 + threadIdx.x;
    if (i < 6 * G3) {
        int g = i % G3;
        float sc = (g < 512) ? NLOG2E : P2LOG2E;
        o[i] = sc * (bi[i] + (g < 512 ? bh[i] : 0.0f));
    }
}

// bhns[l][j] = 2log2e * b_hh[l][512+j]
__global__ void bhn_prep(const float* __restrict__ bh, float* __restrict__ o) {
    int l = blockIdx.x, j = threadIdx.x;
    o[l * 256 + j] = P2LOG2E * bh[l * G3 + 512 + j];
}

// -------- scan PAIR role: one block = (layer l, batch groups g0 and g0+1), 8 waves ----
// Two INDEPENDENT recurrence chains of the SAME layer share one block (and thus one
// resident weight set wf[6][7] + one kf7 LDS slab). Each step interval processes
// A then B back-to-back in one basic block -> the compiler interleaves B's MFMAs into
// A's trans-activation gaps (in-order issue can't do this across steps of ONE chain).
// This attacks the measured latency-bound regime (R9: 1 wave/SIMD = 2x slower than 2).
// Single-buffer h per group (reads phase, barrier, writes phase, barrier).
// h in FR order: FR(k,b) = (k*16+b)*8 f16. ip in lane-fragment order (see worker).
__device__ void scan_pair(const f16* __restrict__ ipring, f16* __restrict__ yring,
                          const f16* __restrict__ whh, const float* __restrict__ bhns,
                          const float* __restrict__ h0, float* __restrict__ out,
                          int* flags, char* smem, int l, int g0, int tid) {
    f16* wlds = (f16*)smem;                    // [48 KB) kf=7 slab
    f16* hbA = (f16*)(smem + WLDS_BYTES);      // [8 KB) h group A
    f16* hbB = (f16*)(smem + WLDS_BYTES + 8192);
    const int wv = tid >> 6, lane = tid & 63;
    const int quad = lane >> 4, b = lane & 15;
    const int gbase = 32 * wv + quad * 4;
    const int lgA = l * 4 + g0, lgB = lgA + 1;
    const int kk0 = 4 * wv + (quad >> 1);
    const int wsub = (quad & 1) * 4;
    long budget = SPIN_BUDGET;

    // A-fragments: rows = (i>>1)*256 + 32wv + (i&1)*16 + b ; k = kf*32 + quad*8
    f16x8 wf[6][7];
    #pragma unroll
    for (int i = 0; i < 6; ++i) {
        const f16* wp = whh + (long)l * G3 * HID
                      + ((i >> 1) * 256 + 32 * wv + (i & 1) * 16 + b) * 256 + quad * 8;
        #pragma unroll
        for (int kf = 0; kf < 7; ++kf)
            wf[i][kf] = opaque(*(const f16x8*)(wp + kf * 32));
        {   // kf 7 -> LDS slab (1 KB per (wv,i) fragment), shared by both groups
            f16x8 v = *(const f16x8*)(wp + 7 * 32);
            *(f16x8*)(&wlds[((wv * 6 + i) * 64 + lane) * 8]) = v;
        }
    }
    f32x4 bhn[2];
    bhn[0] = *(const f32x4*)(bhns + l * 256 + gbase);
    bhn[1] = *(const f32x4*)(bhns + l * 256 + gbase + 16);

    {   // h0 -> both group buffers in FR layout (512 threads cover 32 kgrp x 16 b)
        int k = tid >> 4, bb = tid & 15;
        #pragma unroll
        for (int grp = 0; grp < 2; ++grp) {
            const float* hp = h0 + (long)(l * 64 + (g0 + grp) * 16 + bb) * HID + k * 8;
            f32x4 v0 = *(const f32x4*)hp;
            f32x4 v1 = *(const f32x4*)(hp + 4);
            f16x8 h8 = { (f16)v0[0], (f16)v0[1], (f16)v0[2], (f16)v0[3],
                         (f16)v1[0], (f16)v1[1], (f16)v1[2], (f16)v1[3] };
            f16* hb = grp ? hbB : hbA;
            *(f16x8*)(&hb[(k * 16 + bb) * 8]) = h8;
        }
    }
    __syncthreads();

    const int lane_off = (wv * 4 + quad) * 128 + b * 8;   // lane slot in a gate block
    const int hro0 = (kk0 * 16 + b) * 8 + wsub;           // lane's own h, s=0
    const int hro1 = ((kk0 + 2) * 16 + b) * 8 + wsub;     // s=1

    for (int w = 0; w < NWIN; ++w) {
        if (l < 5 && w >= NRING) {
            wait4_ge(flags + F_YC(lgA, 0), w - NRING + 1, tid, budget);
            wait4_ge(flags + F_YC(lgB, 0), w - NRING + 1, tid, budget);
        }
        wait4_ge(flags + F_IPP(lgA, 0), w + 1, tid, budget);
        wait4_ge(flags + F_IPP(lgB, 0), w + 1, tid, budget);
        const int slot = w & (NRING - 1);
        const f16* iptA = ipring + (long)(lgA * NRING + slot) * IPSLOT + lane_off;
        const f16* iptB = ipring + (long)(lgB * NRING + slot) * IPSLOT + lane_off;
        f16* ycA = yring + (((long)lgA * NRING + slot) * 512 + b) * HID + gbase;
        f16* ycB = yring + (((long)lgB * NRING + slot) * 512 + b) * HID + gbase;
        f16x8 pA0 = *(const f16x8*)(iptA);
        f16x8 pA1 = *(const f16x8*)(iptA + 4096);
        f16x8 pA2 = *(const f16x8*)(iptA + 8192);
        f16x8 pB0 = *(const f16x8*)(iptB);
        f16x8 pB1 = *(const f16x8*)(iptB + 4096);
        f16x8 pB2 = *(const f16x8*)(iptB + 8192);
        for (int t = 0; t < WS; ++t) {
            f16x4 hnA[2], hnB[2];
            // ================= group A compute =================
            {
                f32x4 acc[6];
                acc[0] = acc[1] = acc[2] = acc[3] = (f32x4){0.f, 0.f, 0.f, 0.f};
                acc[4] = bhn[0];
                acc[5] = bhn[1];
                #pragma unroll
                for (int kf = 0; kf < 7; ++kf) {
                    f16x8 hf = *(const f16x8*)(&hbA[((kf * 4 + quad) * 16 + b) * 8]);
                    #pragma unroll
                    for (int i = 0; i < 6; ++i)
                        acc[i] = __builtin_amdgcn_mfma_f32_16x16x32_f16(
                            wf[i][kf], hf, acc[i], 0, 0, 0);
                }
                {
                    f16x8 hf = *(const f16x8*)(&hbA[((28 + quad) * 16 + b) * 8]);
                    #pragma unroll
                    for (int i = 0; i < 6; ++i) {
                        f16x8 wl = *(const f16x8*)(&wlds[((wv * 6 + i) * 64 + lane) * 8]);
                        acc[i] = __builtin_amdgcn_mfma_f32_16x16x32_f16(
                            wl, hf, acc[i], 0, 0, 0);
                    }
                }
                f16x4 hp0 = *(const f16x4*)(&hbA[hro0]);
                f16x4 hp1 = *(const f16x4*)(&hbA[hro1]);
                #pragma unroll
                for (int s = 0; s < 2; ++s) {
                    f16x4 hps = s ? hp1 : hp0;
                    #pragma unroll
                    for (int r = 0; r < 4; ++r) {
                        float rr = frcp(1.0f + fexp2(acc[s][r] + (float)pA0[s * 4 + r]));
                        float zz = frcp(1.0f + fexp2(acc[2 + s][r] + (float)pA1[s * 4 + r]));
                        float tt = frcp(1.0f + fexp2((float)pA2[s * 4 + r] + rr * acc[4 + s][r]));
                        float nn = 1.0f - 2.0f * tt;
                        hnA[s][r] = (f16)(nn + zz * ((float)hps[r] - nn));
                    }
                }
                if (t + 1 < WS) iptA += IPT;
                pA0 = *(const f16x8*)(iptA);
                pA1 = *(const f16x8*)(iptA + 4096);
                pA2 = *(const f16x8*)(iptA + 8192);
            }
            // ================= group B compute (independent stream) =================
            {
                f32x4 acc[6];
                acc[0] = acc[1] = acc[2] = acc[3] = (f32x4){0.f, 0.f, 0.f, 0.f};
                acc[4] = bhn[0];
                acc[5] = bhn[1];
                #pragma unroll
                for (int kf = 0; kf < 7; ++kf) {
                    f16x8 hf = *(const f16x8*)(&hbB[((kf * 4 + quad) * 16 + b) * 8]);
                    #pragma unroll
                    for (int i = 0; i < 6; ++i)
                        acc[i] = __builtin_amdgcn_mfma_f32_16x16x32_f16(
                            wf[i][kf], hf, acc[i], 0, 0, 0);
                }
                {
                    f16x8 hf = *(const f16x8*)(&hbB[((28 + quad) * 16 + b) * 8]);
                    #pragma unroll
                    for (int i = 0; i < 6; ++i) {
                        f16x8 wl = *(const f16x8*)(&wlds[((wv * 6 + i) * 64 + lane) * 8]);
                        acc[i] = __builtin_amdgcn_mfma_f32_16x16x32_f16(
                            wl, hf, acc[i], 0, 0, 0);
                    }
                }
                f16x4 hp0 = *(const f16x4*)(&hbB[hro0]);
                f16x4 hp1 = *(const f16x4*)(&hbB[hro1]);
                #pragma unroll
                for (int s = 0; s < 2; ++s) {
                    f16x4 hps = s ? hp1 : hp0;
                    #pragma unroll
                    for (int r = 0; r < 4; ++r) {
                        float rr = frcp(1.0f + fexp2(acc[s][r] + (float)pB0[s * 4 + r]));
                        float zz = frcp(1.0f + fexp2(acc[2 + s][r] + (float)pB1[s * 4 + r]));
                        float tt = frcp(1.0f + fexp2((float)pB2[s * 4 + r] + rr * acc[4 + s][r]));
                        float nn = 1.0f - 2.0f * tt;
                        hnB[s][r] = (f16)(nn + zz * ((float)hps[r] - nn));
                    }
                }
                if (t + 1 < WS) iptB += IPT;
                pB0 = *(const f16x8*)(iptB);
                pB1 = *(const f16x8*)(iptB + 4096);
                pB2 = *(const f16x8*)(iptB + 8192);
            }
            bar_lgkm();                         // all h(t-1) reads complete
            // ================= write phase =================
            *(f16x4*)(&hbA[hro0]) = hnA[0];
            *(f16x4*)(&hbA[hro1]) = hnA[1];
            *(f16x4*)(&hbB[hro0]) = hnB[0];
            *(f16x4*)(&hbB[hro1]) = hnB[1];
            if (l < 5) {
                *(f16x4*)(ycA) = hnA[0];
                *(f16x4*)(ycA + 16) = hnA[1];
                *(f16x4*)(ycB) = hnB[0];
                *(f16x4*)(ycB + 16) = hnB[1];
            }
            ycA += 16 * HID;
            ycB += 16 * HID;
            bar_lgkm();                         // h(t) visible before next reads
        }
        __syncthreads();                        // full drain (vmcnt) before publish
        if (tid == 0) {
            st_rel(flags + F_IPCONS(lgA), w + 1);
            st_rel(flags + F_IPCONS(lgB), w + 1);
            if (l < 5) {
                st_rel(flags + F_YPROG(lgA), w + 1);
                st_rel(flags + F_YPROG(lgB), w + 1);
            }
        }
    }
    {   // final h -> out (f32), both groups
        int k = tid >> 4, bb = tid & 15;
        #pragma unroll
        for (int grp = 0; grp < 2; ++grp) {
            f16* hb = grp ? hbB : hbA;
            f16x8 h8 = *(const f16x8*)(&hb[(k * 16 + bb) * 8]);
            float* op = out + (long)(l * 64 + (g0 + grp) * 16 + bb) * HID + k * 8;
            f32x4 v0 = { (float)h8[0], (float)h8[1], (float)h8[2], (float)h8[3] };
            f32x4 v1 = { (float)h8[4], (float)h8[5], (float)h8[6], (float)h8[7] };
            *(f32x4*)op = v0;
            *(f32x4*)(op + 4) = v1;
        }
    }
}

// -------- worker role: ip GEMM, 8 waves, one 128-row m-tile (q) per window -------------
// (unchanged from R8) Epilogue: pre-scale + scatter into the lane-fragment ip layout.
template<int K>
__device__ void worker_role(const f16* __restrict__ src, bool is_x, int g,
                            const f16* __restrict__ Wl, const float* __restrict__ bias,
                            f16* __restrict__ dstb, int* flags,
                            int lay, int lg, int plg, int q,
                            char* smem, int tid) {
    f16* As = (f16*)smem;                      // [128][K]
    const int wv = tid >> 6, lane = tid & 63;
    const int quad = lane >> 4, l16 = lane & 15;
    const int mi = wv & 3, ni = wv >> 2;
    constexpr int CPR = K / 8;
    long budget = SPIN_BUDGET;

    for (int w = 0; w < NWIN; ++w) {
        if (lay > 0) wait_ge(flags + F_YPROG(plg), w + 1, tid, budget);
        if (w >= NRING) wait_ge(flags + F_IPCONS(lg), w - NRING + 1, tid, budget);
        const int slot = w & (NRING - 1);
        f16* dst = dstb + (long)slot * IPSLOT;
        #pragma unroll
        for (int it = 0; it < (128 * CPR) / 512; ++it) {
            int idx = it * 512 + tid;
            int row = idx / CPR, c8 = idx % CPR;
            int wr = q * 128 + row;
            long soff;
            if (is_x) soff = ((long)(w * WS + (wr >> 4)) * 64 + g * 16 + (wr & 15)) * K + c8 * 8;
            else      soff = ((long)slot * 512 + wr) * K + c8 * 8;
            f16x8 v = *(const f16x8*)(src + soff);
            *(f16x8*)(&As[row * K + (c8 ^ (row & 7)) * 8]) = v;
        }
        __syncthreads();
        for (int nt = 0; nt < 6; ++nt) {
            const int cbase = nt * 128 + ni * 64;
            f16x8 bc[4], bn[4];
            #pragma unroll
            for (int ns = 0; ns < 4; ++ns)
                bc[ns] = *(const f16x8*)(Wl + (long)(cbase + ns * 16 + l16) * K + quad * 8);
            f32x4 acc[2][4];
            #pragma unroll
            for (int i = 0; i < 2; ++i)
                #pragma unroll
                for (int j = 0; j < 4; ++j) acc[i][j] = (f32x4){0.f, 0.f, 0.f, 0.f};
            #pragma unroll
            for (int kf = 0; kf < K / 32; ++kf) {
                if (kf + 1 < K / 32) {
                    #pragma unroll
                    for (int ns = 0; ns < 4; ++ns)
                        bn[ns] = *(const f16x8*)(Wl + (long)(cbase + ns * 16 + l16) * K
                                                 + (kf + 1) * 32 + quad * 8);
                }
                f16x8 af[2];
                #pragma unroll
                for (int ms = 0; ms < 2; ++ms) {
                    int row = 32 * mi + 16 * ms + l16;
                    int c8 = (kf * 4 + quad) ^ (row & 7);
                    af[ms] = *(const f16x8*)(&As[row * K + c8 * 8]);
                }
                #pragma unroll
                for (int ms = 0; ms < 2; ++ms)
                    #pragma unroll
                    for (int ns = 0; ns < 4; ++ns)
                        acc[ms][ns] = __builtin_amdgcn_mfma_f32_16x16x32_f16(
                            af[ms], bc[ns], acc[ms][ns], 0, 0, 0);
                #pragma unroll
                for (int ns = 0; ns < 4; ++ns) bc[ns] = bn[ns];
            }
            #pragma unroll
            for (int ns = 0; ns < 4; ++ns) {
                int col = cbase + ns * 16 + l16;
                float bv = bias[col];
                float sc = (col < 512) ? NLOG2E : P2LOG2E;
                int gate = col >> 8, j = col & 255;
                int wv2 = j >> 5, rem = j & 31;
                int s2 = rem >> 4, q2 = (rem & 15) >> 2, r2 = rem & 3;
                #pragma unroll
                for (int ms = 0; ms < 2; ++ms) {
                    int t2 = q * 8 + 2 * mi + ms;
                    f16* dp = dst + t2 * IPT + ((gate * 8 + wv2) * 4 + q2) * 128
                            + s2 * 4 + r2;
                    #pragma unroll
                    for (int r = 0; r < 4; ++r)
                        dp[(quad * 4 + r) * 8] = (f16)(acc[ms][ns][r] * sc + bv);
                }
            }
        }
        __syncthreads();                        // drains ip stores + protects As WAR
        if (tid == 0) {
            st_rel(flags + F_IPP(lg, q), w + 1);
            if (lay > 0) st_rel(flags + F_YC(plg, q), w + 1);
        }
    }
}

// XCD-affine decode: bid = xcd + 8*j, 3 lg per XCD, 5 roles (1 scan + 4 workers) per lg.
// Scan runs only for even g (handles g and g+1); odd-g scan slots exit.
// waves_per_eu(2,2): 256-reg unified budget keeps the shared weight set resident.
__global__ __launch_bounds__(512) __attribute__((amdgpu_waves_per_eu(2, 2)))
void gru_fused(
        const f16* __restrict__ xh, const f16* __restrict__ wih,
        const f16* __restrict__ whh, const float* __restrict__ biasc,
        const float* __restrict__ bhns, const float* __restrict__ h0,
        float* __restrict__ out, f16* __restrict__ yring, f16* __restrict__ ipring,
        int* flags) {
    __shared__ __align__(16) char smem[SMEM_BYTES];
    const int bid = blockIdx.x, tid = threadIdx.x;
    const int x = bid & 7, j = bid >> 3;
    const int lgrp = j / 5, role = j % 5;
    const int lg = lgrp * 8 + x;                // 0..23, same-XCD as its workers
    const int l = lg >> 2, g = lg & 3;
    if (role == 0) {
        if (g & 1) return;                      // pair handled by the even-g block
        scan_pair(ipring, yring, whh, bhns, h0, out, flags, smem, l, g, tid);
    } else {
        const int q = role - 1;
        const float* bias = biasc + l * G3;
        f16* dstb = ipring + (long)lg * NRING * IPSLOT;
        if (l == 0) {
            worker_role<128>(xh, true, g, wih, bias, dstb, flags,
                             0, lg, 0, q, smem, tid);
        } else {
            int plg = (l - 1) * 4 + g;
            const f16* Wl = wih + 768 * 128 + (long)(l - 1) * G3 * HID;
            const f16* src = yring + (long)plg * NRING * 512 * HID;
            worker_role<256>(src, false, g, Wl, bias, dstb, flags,
                             l, lg, plg, q, smem, tid);
        }
    }
}

extern "C" void kernel_launch(void* const* d_in, const int* in_sizes, int n_in,
                              void* d_out, int out_size, void* d_ws, size_t ws_size,
                              hipStream_t stream) {
    const float* x     = (const float*)d_in[0];   // [2048,64,128]
    const float* h0    = (const float*)d_in[1];   // [6,64,256]
    const float* w_ih0 = (const float*)d_in[2];   // [768,128]
    const float* w_ihr = (const float*)d_in[3];   // [5,768,256]
    const float* w_hh  = (const float*)d_in[4];   // [6,768,256]
    const float* b_ih  = (const float*)d_in[5];   // [6,768]
    const float* b_hh  = (const float*)d_in[6];   // [6,768]
    float* out = (float*)d_out;                   // [6,64,256]

    char* p = (char*)d_ws;
    f16* xh      = (f16*)p;   p += (long)T_TOT * BATCH * 128 * 2;        // 33.5 MB
    f16* wih     = (f16*)p;   p += (long)(768 * 128 + 5 * 768 * 256) * 2;
    f16* whh     = (f16*)p;   p += (long)6 * 768 * 256 * 2;
    float* biasc = (float*)p; p += (long)6 * G3 * 4;
    float* bhns  = (float*)p; p += (long)6 * 256 * 4;
    f16* yring   = (f16*)p;   p += (long)20 * NRING * 512 * HID * 2;     // 21 MB
    f16* ipring  = (f16*)p;   p += (long)24 * NRING * IPSLOT * 2;        // 75.5 MB
    int* flags   = (int*)p;   p += 1024;

    hipMemsetAsync(flags, 0, 1024, stream);
    cvt_f16<<<16384, 256, 0, stream>>>(x, xh, T_TOT * BATCH * 128);
    cvt_f16<<<96, 256, 0, stream>>>(w_ih0, wih, 768 * 128);
    cvt_f16<<<960, 256, 0, stream>>>(w_ihr, wih + 768 * 128, 5 * 768 * 256);
    cvt_whh<<<1152, 256, 0, stream>>>(w_hh, whh, 6 * 768 * 256);
    bias_prep<<<18, 256, 0, stream>>>(b_ih, b_hh, biasc);
    bhn_prep<<<6, 256, 0, stream>>>(b_hh, bhns);

    gru_fused<<<120, 512, 0, stream>>>(xh, wih, whh, biasc, bhns, h0, out,
                                       yring, ipring, flags);
}

// Round 11
// 4801.466 us; speedup vs baseline: 6.3933x; 6.3933x over previous
//
#include <hip/hip_runtime.h>

typedef _Float16 f16;
typedef _Float16 f16x8 __attribute__((ext_vector_type(8)));
typedef _Float16 f16x4 __attribute__((ext_vector_type(4)));
typedef float f32x4 __attribute__((ext_vector_type(4)));

#define T_TOT 2048
#define BATCH 64
#define HID 256
#define G3 768
#define WS 32
#define NWIN 64
#define NRING 4
#define IPT 12288                   // f16 per timestep per lg: 3 gates x 256 j x 16 b
#define IPSLOT (WS * IPT)           // 393216 f16 per ring slot

#define NLOG2E -1.44269504088896f   // -log2(e): sigmoid pre-scale
#define P2LOG2E 2.88539008177793f   // +2*log2(e): tanh pre-scale

#define SPIN_BUDGET 20000000L       // bails instead of hanging the queue

// LDS map (64 KB total — the known-good size on this harness):
//   [0, 48K)  scan: weight slab for kf=7  /  worker: As tile (uses [0,64K))
//   [48K,64K) scan: h double buffer
#define WLDS_BYTES 49152
#define SMEM_BYTES 65536

// flags (monotone single-writer counters), zero-initialized:
#define F_YPROG(lg)   (lg)                    // scan l: y windows produced
#define F_IPCONS(lg)  (24 + (lg))             // scan l: ip windows consumed
#define F_IPP(lg,q)   (48 + (lg)*4 + (q))     // worker q of layer l: ip produced
#define F_YC(lg,q)    (144 + (lg)*4 + (q))    // worker q of layer l+1: y consumed

__device__ __forceinline__ float fexp2(float x) { return __builtin_amdgcn_exp2f(x); }
__device__ __forceinline__ float frcp(float x) { return __builtin_amdgcn_rcpf(x); }

// opaque identity: makes a loaded value NON-rematerializable so the register
// allocator must keep it resident instead of re-loading from memory each use
__device__ __forceinline__ f16x8 opaque(f16x8 v) {
    f32x4 t = __builtin_bit_cast(f32x4, v);
    asm volatile("" : "+v"(t));
    return __builtin_bit_cast(f16x8, t);
}

__device__ __forceinline__ void st_rel(int* p, int v) {
    __hip_atomic_store(p, v, __ATOMIC_RELEASE, __HIP_MEMORY_SCOPE_AGENT);
}
__device__ __forceinline__ int ld_rlx(int* p) {
    return __hip_atomic_load(p, __ATOMIC_RELAXED, __HIP_MEMORY_SCOPE_AGENT);
}
__device__ __forceinline__ void wait_ge(int* f, int target, int tid, long& budget) {
    if (tid == 0) {
        while (ld_rlx(f) < target) {
            if (--budget < 0) break;
            __builtin_amdgcn_s_sleep(4);
        }
        __builtin_amdgcn_fence(__ATOMIC_ACQUIRE, "agent");
    }
    __syncthreads();
}
__device__ __forceinline__ void wait4_ge(int* f, int target, int tid, long& budget) {
    if (tid == 0) {
        #pragma unroll
        for (int q = 0; q < 4; ++q)
            while (ld_rlx(f + q) < target) {
                if (--budget < 0) break;
                __builtin_amdgcn_s_sleep(4);
            }
        __builtin_amdgcn_fence(__ATOMIC_ACQUIRE, "agent");
    }
    __syncthreads();
}
// barrier draining ONLY LDS ops; global loads/stores stay in flight
__device__ __forceinline__ void bar_lgkm() {
    asm volatile("s_waitcnt lgkmcnt(0)\n\ts_barrier" ::: "memory");
}

__global__ void cvt_f16(const float* __restrict__ s, f16* __restrict__ d, int n) {
    int i = (blockIdx.x * 256 + threadIdx.x) * 4;
    if (i + 3 < n) {
        f32x4 v = *(const f32x4*)(s + i);
        f16x4 o = { (f16)v[0], (f16)v[1], (f16)v[2], (f16)v[3] };
        *(f16x4*)(d + i) = o;
    }
}

// W_hh with gate pre-scale: rows<512 (r,z) * -log2e; rows>=512 (n) * 2log2e
__global__ void cvt_whh(const float* __restrict__ s, f16* __restrict__ d, int n) {
    int i = (blockIdx.x * 256 + threadIdx.x) * 4;
    if (i + 3 < n) {
        int row = (i >> 8) % G3;
        float sc = (row < 512) ? NLOG2E : P2LOG2E;
        f32x4 v = *(const f32x4*)(s + i);
        f16x4 o = { (f16)(v[0] * sc), (f16)(v[1] * sc), (f16)(v[2] * sc), (f16)(v[3] * sc) };
        *(f16x4*)(d + i) = o;
    }
}

// biasc[l][g] = scale_g * (b_ih + b_hh for r,z ; b_ih only for n)
__global__ void bias_prep(const float* __restrict__ bi, const float* __restrict__ bh,
                          float* __restrict__ o) {
    int i = blockIdx.x * 256 + threadIdx.x;
    if (i < 6 * G3) {
        int g = i % G3;
        float sc = (g < 512) ? NLOG2E : P2LOG2E;
        o[i] = sc * (bi[i] + (g < 512 ? bh[i] : 0.0f));
    }
}

// bhns[l][j] = 2log2e * b_hh[l][512+j]
__global__ void bhn_prep(const float* __restrict__ bh, float* __restrict__ o) {
    int l = blockIdx.x, j = threadIdx.x;
    o[l * 256 + j] = P2LOG2E * bh[l * G3 + 512 + j];
}

// ---------------- scan role: one block = (layer l, batch group g of 16), 8 waves -------
// Weight residency split (the bottleneck of rounds 0-3 was per-step W_hh re-fetch
// through the CU's L2 port, ~6000 cy/step):
//   kf 0..6 -> REGISTERS: wf[6][7] = 42 frags x 4 VGPR = 168 VGPR/wave (336 KB/CU),
//              each pinned via opaque() so the allocator cannot rematerialize the load.
//   kf 7    -> LDS slab: 8 wv x 6 i x 1 KB = 48 KB/CU, loaded ONCE.
// amdgpu_waves_per_eu(2,2) pins the 256-VGPR budget.
// h in LDS in FRAGMENT ORDER: FR(k,b) = (k*16+b)*8 f16.
// ip in LANE-FRAGMENT ORDER: ip2[t][gate][wv][quad][b][8] -> each lane reads one f16x8.
__device__ void scan_role(const f16* __restrict__ ipring, f16* __restrict__ yring,
                          const f16* __restrict__ whh, const float* __restrict__ bhns,
                          const float* __restrict__ h0, float* __restrict__ out,
                          int* flags, char* smem, int l, int g, int tid) {
    f16* wlds = (f16*)smem;                    // [48 KB) weight slab kf=7
    f16* hb = (f16*)(smem + WLDS_BYTES);       // h double buffer [2][4096] f16 = 16 KB
    const int wv = tid >> 6, lane = tid & 63;
    const int quad = lane >> 4, b = lane & 15;
    const int gbase = 32 * wv + quad * 4;
    const int lg = l * 4 + g;
    const int kk0 = 4 * wv + (quad >> 1);      // gate-write chunk base (s adds 2)
    const int wsub = (quad & 1) * 4;           // 8B sub-offset inside chunk
    long budget = SPIN_BUDGET;

    // A-fragments: rows = (i>>1)*256 + 32wv + (i&1)*16 + b ; k = kf*32 + quad*8
    f16x8 wf[6][7];
    #pragma unroll
    for (int i = 0; i < 6; ++i) {
        const f16* wp = whh + (long)l * G3 * HID
                      + ((i >> 1) * 256 + 32 * wv + (i & 1) * 16 + b) * 256 + quad * 8;
        #pragma unroll
        for (int kf = 0; kf < 7; ++kf)
            wf[i][kf] = opaque(*(const f16x8*)(wp + kf * 32));
        {   // kf 7 -> LDS slab (1 KB per (wv,i) fragment)
            f16x8 v = *(const f16x8*)(wp + 7 * 32);
            *(f16x8*)(&wlds[((wv * 6 + i) * 64 + lane) * 8]) = v;
        }
    }
    f32x4 bhn[2];
    bhn[0] = *(const f32x4*)(bhns + l * 256 + gbase);
    bhn[1] = *(const f32x4*)(bhns + l * 256 + gbase + 16);

    {   // h0 -> buffer 0 in FR layout
        int k = tid >> 4, bb = tid & 15;
        const float* hp = h0 + (long)(l * 64 + g * 16 + bb) * HID + k * 8;
        f32x4 v0 = *(const f32x4*)hp;
        f32x4 v1 = *(const f32x4*)(hp + 4);
        f16x8 h8 = { (f16)v0[0], (f16)v0[1], (f16)v0[2], (f16)v0[3],
                     (f16)v1[0], (f16)v1[1], (f16)v1[2], (f16)v1[3] };
        *(f16x8*)(&hb[(k * 16 + bb) * 8]) = h8;
    }
    f16x4 hp_[2];                               // lane's own h slice, register-resident
    #pragma unroll
    for (int s = 0; s < 2; ++s) {
        f32x4 v = *(const f32x4*)(h0 + (long)(l * 64 + g * 16 + b) * HID + gbase + s * 16);
        hp_[s] = (f16x4){ (f16)v[0], (f16)v[1], (f16)v[2], (f16)v[3] };
    }
    __syncthreads();                            // drains wlds + h0 ds_writes

    const int lane_off = (wv * 4 + quad) * 128 + b * 8;   // lane's slot inside a gate blk
    for (int w = 0; w < NWIN; ++w) {
        if (l < 5 && w >= NRING)
            wait4_ge(flags + F_YC(lg, 0), w - NRING + 1, tid, budget);
        wait4_ge(flags + F_IPP(lg, 0), w + 1, tid, budget);
        const int slot = w & (NRING - 1);
        const f16* ipt = ipring + (long)(lg * NRING + slot) * IPSLOT + lane_off;
        f16* yc = yring + (((long)lg * NRING + slot) * 512 + b) * HID + gbase;
        f16x8 p0 = *(const f16x8*)(ipt);              // prime t=0: r, z, n chunks
        f16x8 p1 = *(const f16x8*)(ipt + 4096);
        f16x8 p2 = *(const f16x8*)(ipt + 8192);
        for (int tp = 0; tp < WS; tp += 2) {
            #pragma unroll
            for (int u = 0; u < 2; ++u) {
                const int rdo = u * 4096;       // read h(t-1) from buffer u
                const int wro = (u ^ 1) * 4096; // write h(t) to buffer u^1
                f32x4 acc[6];
                acc[0] = acc[1] = acc[2] = acc[3] = (f32x4){0.f, 0.f, 0.f, 0.f};
                acc[4] = bhn[0];                // pre-scaled b_hh_n in acc init
                acc[5] = bhn[1];
                #pragma unroll
                for (int kf = 0; kf < 7; ++kf) {   // register-resident weights
                    f16x8 hf = *(const f16x8*)(&hb[rdo + ((kf * 4 + quad) * 16 + b) * 8]);
                    #pragma unroll
                    for (int i = 0; i < 6; ++i)
                        acc[i] = __builtin_amdgcn_mfma_f32_16x16x32_f16(
                            wf[i][kf], hf, acc[i], 0, 0, 0);
                }
                {   // kf 7: LDS-resident weights
                    f16x8 hf = *(const f16x8*)(&hb[rdo + ((7 * 4 + quad) * 16 + b) * 8]);
                    #pragma unroll
                    for (int i = 0; i < 6; ++i) {
                        f16x8 wl = *(const f16x8*)(&wlds[((wv * 6 + i) * 64 + lane) * 8]);
                        acc[i] = __builtin_amdgcn_mfma_f32_16x16x32_f16(
                            wl, hf, acc[i], 0, 0, 0);
                    }
                }
                f16x4 hnew[2];
                #pragma unroll
                for (int s = 0; s < 2; ++s) {
                    #pragma unroll
                    for (int r = 0; r < 4; ++r) {
                        float rr = frcp(1.0f + fexp2(acc[s][r] + (float)p0[s * 4 + r]));
                        float zz = frcp(1.0f + fexp2(acc[2 + s][r] + (float)p1[s * 4 + r]));
                        float tt = frcp(1.0f + fexp2((float)p2[s * 4 + r] + rr * acc[4 + s][r]));
                        float nn = 1.0f - 2.0f * tt;
                        hnew[s][r] = (f16)(nn + zz * ((float)hp_[s][r] - nn));
                    }
                    hp_[s] = hnew[s];
                    *(f16x4*)(&hb[wro + ((kk0 + 2 * s) * 16 + b) * 8 + wsub]) = hnew[s];
                }
                // prefetch t+1 (clamped); loads issue BEFORE y-store (vmcnt FIFO)
                if (tp + u + 1 < WS) ipt += IPT;
                p0 = *(const f16x8*)(ipt);
                p1 = *(const f16x8*)(ipt + 4096);
                p2 = *(const f16x8*)(ipt + 8192);
                if (l < 5) {
                    *(f16x4*)(yc) = hnew[0];
                    *(f16x4*)(yc + 16) = hnew[1];
                }
                yc += 16 * HID;
                bar_lgkm();                     // LDS-only drain, 1 barrier/step
            }
        }
        __syncthreads();                        // full drain (vmcnt) before publish
        if (tid == 0) {
            st_rel(flags + F_IPCONS(lg), w + 1);
            if (l < 5) st_rel(flags + F_YPROG(lg), w + 1);
        }
    }
    {   // final h (buffer 0 after 2048 steps) -> out (f32)
        int k = tid >> 4, bb = tid & 15;
        f16x8 h8 = *(const f16x8*)(&hb[(k * 16 + bb) * 8]);
        float* op = out + (long)(l * 64 + g * 16 + bb) * HID + k * 8;
        f32x4 v0 = { (float)h8[0], (float)h8[1], (float)h8[2], (float)h8[3] };
        f32x4 v1 = { (float)h8[4], (float)h8[5], (float)h8[6], (float)h8[7] };
        *(f32x4*)op = v0;
        *(f32x4*)(op + 4) = v1;
    }
}

// -------- worker role: ip GEMM, 8 waves, one 128-row m-tile (q) per window -------------
// Epilogue: pre-scale and scatter into the lane-fragment ip layout (see scan_role).
// Window row m = t2*16 + b; for fixed (ms,ns): t2 = q*8+2*mi+ms, b = quad*4+r.
template<int K>
__device__ void worker_role(const f16* __restrict__ src, bool is_x, int g,
                            const f16* __restrict__ Wl, const float* __restrict__ bias,
                            f16* __restrict__ dstb, int* flags,
                            int lay, int lg, int plg, int q,
                            char* smem, int tid) {
    f16* As = (f16*)smem;                      // [128][K]
    const int wv = tid >> 6, lane = tid & 63;
    const int quad = lane >> 4, l16 = lane & 15;
    const int mi = wv & 3, ni = wv >> 2;
    constexpr int CPR = K / 8;
    long budget = SPIN_BUDGET;

    for (int w = 0; w < NWIN; ++w) {
        if (lay > 0) wait_ge(flags + F_YPROG(plg), w + 1, tid, budget);
        if (w >= NRING) wait_ge(flags + F_IPCONS(lg), w - NRING + 1, tid, budget);
        const int slot = w & (NRING - 1);
        f16* dst = dstb + (long)slot * IPSLOT;
        #pragma unroll
        for (int it = 0; it < (128 * CPR) / 512; ++it) {
            int idx = it * 512 + tid;
            int row = idx / CPR, c8 = idx % CPR;
            int wr = q * 128 + row;
            long soff;
            if (is_x) soff = ((long)(w * WS + (wr >> 4)) * 64 + g * 16 + (wr & 15)) * K + c8 * 8;
            else      soff = ((long)slot * 512 + wr) * K + c8 * 8;
            f16x8 v = *(const f16x8*)(src + soff);
            *(f16x8*)(&As[row * K + (c8 ^ (row & 7)) * 8]) = v;
        }
        __syncthreads();
        for (int nt = 0; nt < 6; ++nt) {
            const int cbase = nt * 128 + ni * 64;
            f16x8 bc[4], bn[4];
            #pragma unroll
            for (int ns = 0; ns < 4; ++ns)
                bc[ns] = *(const f16x8*)(Wl + (long)(cbase + ns * 16 + l16) * K + quad * 8);
            f32x4 acc[2][4];
            #pragma unroll
            for (int i = 0; i < 2; ++i)
                #pragma unroll
                for (int j = 0; j < 4; ++j) acc[i][j] = (f32x4){0.f, 0.f, 0.f, 0.f};
            #pragma unroll
            for (int kf = 0; kf < K / 32; ++kf) {
                if (kf + 1 < K / 32) {
                    #pragma unroll
                    for (int ns = 0; ns < 4; ++ns)
                        bn[ns] = *(const f16x8*)(Wl + (long)(cbase + ns * 16 + l16) * K
                                                 + (kf + 1) * 32 + quad * 8);
                }
                f16x8 af[2];
                #pragma unroll
                for (int ms = 0; ms < 2; ++ms) {
                    int row = 32 * mi + 16 * ms + l16;
                    int c8 = (kf * 4 + quad) ^ (row & 7);
                    af[ms] = *(const f16x8*)(&As[row * K + c8 * 8]);
                }
                #pragma unroll
                for (int ms = 0; ms < 2; ++ms)
                    #pragma unroll
                    for (int ns = 0; ns < 4; ++ns)
                        acc[ms][ns] = __builtin_amdgcn_mfma_f32_16x16x32_f16(
                            af[ms], bc[ns], acc[ms][ns], 0, 0, 0);
                #pragma unroll
                for (int ns = 0; ns < 4; ++ns) bc[ns] = bn[ns];
            }
            #pragma unroll
            for (int ns = 0; ns < 4; ++ns) {
                int col = cbase + ns * 16 + l16;
                float bv = bias[col];
                float sc = (col < 512) ? NLOG2E : P2LOG2E;
                // decompose col -> (gate, wv2, s2, quad2, r2) for fragment layout
                int gate = col >> 8, j = col & 255;
                int wv2 = j >> 5, rem = j & 31;
                int s2 = rem >> 4, q2 = (rem & 15) >> 2, r2 = rem & 3;
                #pragma unroll
                for (int ms = 0; ms < 2; ++ms) {
                    int t2 = q * 8 + 2 * mi + ms;
                    f16* dp = dst + t2 * IPT + ((gate * 8 + wv2) * 4 + q2) * 128
                            + s2 * 4 + r2;
                    #pragma unroll
                    for (int r = 0; r < 4; ++r)
                        dp[(quad * 4 + r) * 8] = (f16)(acc[ms][ns][r] * sc + bv);
                }
            }
        }
        __syncthreads();                        // drains ip stores + protects As WAR
        if (tid == 0) {
            st_rel(flags + F_IPP(lg, q), w + 1);
            if (lay > 0) st_rel(flags + F_YC(plg, q), w + 1);
        }
    }
}

// XCD-affine decode: bid = xcd + 8*j, 3 lg per XCD, 5 roles (1 scan + 4 workers) per lg.
// waves_per_eu(2,2): pin 2 waves/SIMD -> 256-VGPR budget so scan weights stay resident.
__global__ __launch_bounds__(512) __attribute__((amdgpu_waves_per_eu(2, 2)))
void gru_fused(
        const f16* __restrict__ xh, const f16* __restrict__ wih,
        const f16* __restrict__ whh, const float* __restrict__ biasc,
        const float* __restrict__ bhns, const float* __restrict__ h0,
        float* __restrict__ out, f16* __restrict__ yring, f16* __restrict__ ipring,
        int* flags) {
    __shared__ __align__(16) char smem[SMEM_BYTES];
    const int bid = blockIdx.x, tid = threadIdx.x;
    const int x = bid & 7, j = bid >> 3;
    const int lgrp = j / 5, role = j % 5;
    const int lg = lgrp * 8 + x;                // 0..23, same-XCD as its workers
    const int l = lg >> 2, g = lg & 3;
    if (role == 0) {
        scan_role(ipring, yring, whh, bhns, h0, out, flags, smem, l, g, tid);
    } else {
        const int q = role - 1;
        const float* bias = biasc + l * G3;
        f16* dstb = ipring + (long)lg * NRING * IPSLOT;
        if (l == 0) {
            worker_role<128>(xh, true, g, wih, bias, dstb, flags,
                             0, lg, 0, q, smem, tid);
        } else {
            int plg = (l - 1) * 4 + g;
            const f16* Wl = wih + 768 * 128 + (long)(l - 1) * G3 * HID;
            const f16* src = yring + (long)plg * NRING * 512 * HID;
            worker_role<256>(src, false, g, Wl, bias, dstb, flags,
                             l, lg, plg, q, smem, tid);
        }
    }
}

extern "C" void kernel_launch(void* const* d_in, const int* in_sizes, int n_in,
                              void* d_out, int out_size, void* d_ws, size_t ws_size,
                              hipStream_t stream) {
    const float* x     = (const float*)d_in[0];   // [2048,64,128]
    const float* h0    = (const float*)d_in[1];   // [6,64,256]
    const float* w_ih0 = (const float*)d_in[2];   // [768,128]
    const float* w_ihr = (const float*)d_in[3];   // [5,768,256]
    const float* w_hh  = (const float*)d_in[4];   // [6,768,256]
    const float* b_ih  = (const float*)d_in[5];   // [6,768]
    const float* b_hh  = (const float*)d_in[6];   // [6,768]
    float* out = (float*)d_out;                   // [6,64,256]

    char* p = (char*)d_ws;
    f16* xh      = (f16*)p;   p += (long)T_TOT * BATCH * 128 * 2;        // 33.5 MB
    f16* wih     = (f16*)p;   p += (long)(768 * 128 + 5 * 768 * 256) * 2;
    f16* whh     = (f16*)p;   p += (long)6 * 768 * 256 * 2;
    float* biasc = (float*)p; p += (long)6 * G3 * 4;
    float* bhns  = (float*)p; p += (long)6 * 256 * 4;
    f16* yring   = (f16*)p;   p += (long)20 * NRING * 512 * HID * 2;     // 21 MB
    f16* ipring  = (f16*)p;   p += (long)24 * NRING * IPSLOT * 2;        // 75.5 MB
    int* flags   = (int*)p;   p += 1024;

    hipMemsetAsync(flags, 0, 1024, stream);
    cvt_f16<<<16384, 256, 0, stream>>>(x, xh, T_TOT * BATCH * 128);
    cvt_f16<<<96, 256, 0, stream>>>(w_ih0, wih, 768 * 128);
    cvt_f16<<<960, 256, 0, stream>>>(w_ihr, wih + 768 * 128, 5 * 768 * 256);
    cvt_whh<<<1152, 256, 0, stream>>>(w_hh, whh, 6 * 768 * 256);
    bias_prep<<<18, 256, 0, stream>>>(b_ih, b_hh, biasc);
    bhn_prep<<<6, 256, 0, stream>>>(b_hh, bhns);

    gru_fused<<<120, 512, 0, stream>>>(xh, wih, whh, biasc, bhns, h0, out,
                                       yring, ipring, flags);
}